// Round 14
// baseline (2526.902 us; speedup 1.0000x reference)
//
#include <hip/hip_runtime.h>

#define TT 512
#define BB 256
#define HH 512
#define FH 2048   // 4*H

typedef __attribute__((ext_vector_type(8))) short short8;
typedef __attribute__((ext_vector_type(4))) short short4v;
typedef __attribute__((ext_vector_type(4))) float f32x4;
typedef __attribute__((ext_vector_type(2))) float f32x2;

__device__ __forceinline__ short f2bf(float f) {
  union { float f; unsigned u; } v; v.f = f;
  unsigned r = v.u + 0x7fffu + ((v.u >> 16) & 1u);   // RNE
  return (short)(r >> 16);
}
__device__ __forceinline__ unsigned short f2h(float f) {
  union { _Float16 h; unsigned short u; } v;
  v.h = (_Float16)f;
  return v.u;
}
__device__ __forceinline__ float h2f(unsigned short u) {
  union { _Float16 h; unsigned short u; } v;
  v.u = u;
  return (float)v.h;
}

__device__ __forceinline__ float sigm(float x) {
  return 1.f / (1.f + __expf(-x));
}
__device__ __forceinline__ float tanh_fast(float x) {
  float e = __expf(2.f * x);
  return 1.f - 2.f / (e + 1.f);
}

// LDS-tiled coalesced weight transpose: Wi/Wh (512 k x 2048 col, fp32, row-major)
// -> WiT/WhT (2048 col x 512 k, bf16). 64x64 tiles; both global sides coalesced.
__global__ __launch_bounds__(256) void prep_w(
    const float* __restrict__ Wi, const float* __restrict__ Wh,
    short* __restrict__ WiT, short* __restrict__ WhT) {
  __shared__ short t[64][65];     // [k][c], +1 pad
  const int w = blockIdx.x >> 8;            // 0: Wi, 1: Wh
  const int tile = blockIdx.x & 255;
  const int c0 = (tile & 31) * 64;
  const int k0 = (tile >> 5) * 64;
  const float* src = w ? Wh : Wi;
  short* dst = w ? WhT : WiT;
  const int tid = threadIdx.x;

  {
    const int r = tid >> 2;                 // 0..63
    const int cq = (tid & 3) * 16;
#pragma unroll
    for (int i = 0; i < 4; ++i) {
      f32x4 v = *(const f32x4*)(src + (size_t)(k0 + r) * FH + c0 + cq + i * 4);
      short4v s = { f2bf(v[0]), f2bf(v[1]), f2bf(v[2]), f2bf(v[3]) };
      *(short4v*)(&t[r][cq + i * 4]) = s;
    }
  }
  __syncthreads();

  {
    const int c = tid >> 2;                 // 0..63
    const int kq = (tid & 3) * 16;
    short8 o0, o1;
#pragma unroll
    for (int e = 0; e < 8; ++e) {
      o0[e] = t[kq + e][c];
      o1[e] = t[kq + 8 + e][c];
    }
    short* d = dst + (size_t)(c0 + c) * 512 + k0 + kq;
    *(short8*)d = o0;
    *(short8*)(d + 8) = o1;
  }
}

// prep misc: packed h init, c init, counters, fallback h.
__global__ void prep_kernel(const float* __restrict__ h0, const float* __restrict__ c0,
                            unsigned* __restrict__ hb0, float* __restrict__ cb,
                            short* __restrict__ hbf, int* __restrict__ cnt) {
  int idx = blockIdx.x * blockDim.x + threadIdx.x;
  int stride = gridDim.x * blockDim.x;
  for (int i = idx; i < BB * HH; i += stride) {
    hbf[i] = f2bf(h0[i]);
    cb[i] = c0[i];
  }
  for (int i = idx; i < BB * 256; i += stride) {
    int row = i >> 8;
    int cpx = (i & 255) * 2;
    hb0[i] = (unsigned)(unsigned short)f2bf(h0[(size_t)row * HH + cpx]) |
             ((unsigned)(unsigned short)f2bf(h0[(size_t)row * HH + cpx + 1]) << 16);
  }
  for (int i = idx; i < 8 * TT; i += stride) cnt[i] = 0;
}

// 128x128-tile GEMM: Gx16 = fp16(X @ WiT^T + bias). Reg-staged swizzled LDS
// (fp32 A converted in-flight); XCD-aware flat-grid swizzle for panel L2 reuse.
__global__ __launch_bounds__(256) void precomp_kernel(
    const float* __restrict__ X, const short* __restrict__ WiT,
    const float* __restrict__ bias, unsigned short* __restrict__ Gx,
    int rowBase) {
  __shared__ short As[128 * 64];
  __shared__ short Bs[128 * 64];

  const int tid = threadIdx.x;

  int coltile, rowtile;
  if ((gridDim.x & 127) == 0) {
    const int b = blockIdx.x;
    const int xcd = b & 7;
    const int i = b >> 3;
    rowtile = (i >> 4) * 8 + xcd;
    coltile = i & 15;
  } else {
    coltile = blockIdx.x & 15;
    rowtile = blockIdx.x >> 4;
  }
  const int cb0 = coltile * 128;
  const int rb = rowtile * 128;
  const size_t grow = (size_t)rowBase + rb;

  const int wid = tid >> 6;
  const int lane = tid & 63;
  const int lc = lane & 15;
  const int kg = lane >> 4;
  const int m0 = (wid >> 1) * 64;
  const int n0 = (wid & 1) * 64;

  f32x4 acc[4][4] = {};

  for (int kt = 0; kt < 8; ++kt) {
    const int k0 = kt * 64;
    __syncthreads();
#pragma unroll
    for (int i = 0; i < 4; ++i) {
      const int idx = tid * 4 + i;
      const int row = idx >> 3;
      const int kc = idx & 7;
      const float* ap = X + (grow + row) * 512 + k0 + kc * 8;
      f32x4 u0 = *(const f32x4*)ap;
      f32x4 u1 = *(const f32x4*)(ap + 4);
      short8 av;
#pragma unroll
      for (int e = 0; e < 4; ++e) { av[e] = f2bf(u0[e]); av[e + 4] = f2bf(u1[e]); }
      short8 bv = *(const short8*)(WiT + (size_t)(cb0 + row) * 512 + k0 + kc * 8);
      const int off = (row * 128 + kc * 16) ^ ((row & 7) << 4);
      *(short8*)((char*)As + off) = av;
      *(short8*)((char*)Bs + off) = bv;
    }
    __syncthreads();

    const int sw = (lc & 7) << 4;
#pragma unroll
    for (int ks = 0; ks < 2; ++ks) {
      const int kb = ks * 64 + kg * 16;
      short8 af[4], bf[4];
#pragma unroll
      for (int m = 0; m < 4; ++m)
        af[m] = *(const short8*)((char*)As + (((m0 + m * 16 + lc) * 128 + kb) ^ sw));
#pragma unroll
      for (int n = 0; n < 4; ++n)
        bf[n] = *(const short8*)((char*)Bs + (((n0 + n * 16 + lc) * 128 + kb) ^ sw));
#pragma unroll
      for (int m = 0; m < 4; ++m)
#pragma unroll
        for (int n = 0; n < 4; ++n)
          acc[m][n] = __builtin_amdgcn_mfma_f32_16x16x32_bf16(af[m], bf[n],
                                                              acc[m][n], 0, 0, 0);
    }
  }

#pragma unroll
  for (int n = 0; n < 4; ++n) {
    const int col = cb0 + n0 + n * 16 + lc;
    const float bv = bias[col];
#pragma unroll
    for (int m = 0; m < 4; ++m) {
      const int rloc = rb + m0 + m * 16 + kg * 4;
#pragma unroll
      for (int j = 0; j < 4; ++j)
        Gx[(size_t)(rloc + j) * FH + col] = f2h(acc[m][n][j] + bv);
    }
  }
}

// Persistent step kernel (R11 structure; sync = single counter per (grp,t)):
// 256 blocks = 8 groups x 32 col-groups, 256 threads; MFMA split across 4
// waves (wave = 1 gate x 32 rows); h via relaxed agent atomics; producer
// fetch_add after publish->vmcnt(0)->barrier; wave-0 polls one word, s_sleep(1).
__global__ __launch_bounds__(256) void lstm_persist(
    const int* __restrict__ resets,         // (T,B)
    const short* __restrict__ WhT,          // (2048,512) bf16 bits
    const unsigned short* __restrict__ Gx,  // (ct,B,2048) fp16, bias included
    unsigned* __restrict__ hbA,             // (B,256) u32 bf16-pairs, parity 0
    unsigned* __restrict__ hbB,             // parity 1
    float* __restrict__ cb,                 // (B,H) c state (chunk carry)
    float* __restrict__ out,                // output base
    int* __restrict__ cnt,                  // (8,T) counters
    int t0, int ct) {
  extern __shared__ short whs[];          // 64 gate-cols x 512 k, swizzled (64 KB)
  __shared__ short ah[32 * 512];          // 32 rows x 512 k, swizzled (32 KB)
  __shared__ float gex[4 * 32 * 17];      // gate exchange (8.5 KB)

  const int tid = threadIdx.x;
  const int bid = blockIdx.x;
  const int grp = bid >> 5;          // batch group 0..7
  const int j = bid & 31;            // col group
  const int rb = grp * 32;
  const int hc0 = j * 16;

  const int wid = tid >> 6;
  const int lane = tid & 63;
  const int lc = lane & 15;
  const int kg = lane >> 4;

  // ---- Wh slice -> LDS (once, swizzled) ----
  {
    const int lcol = tid >> 2;            // 0..63 gate-col
    const int part = tid & 3;             // 128-short quarters
    const int g = lcol >> 4;
    const int gcol = g * 512 + hc0 + (lcol & 15);
    const short* src = WhT + (size_t)gcol * 512 + part * 128;
    const int dbase = lcol * 1024 + part * 256;
    const int sw = (lcol & 7) << 4;
#pragma unroll
    for (int it = 0; it < 16; ++it) {
      short8 v = *(const short8*)(src + it * 8);
      *(short8*)((char*)whs + ((dbase + it * 16) ^ sw)) = v;
    }
  }

  // ---- epilogue ownership: row = tid>>3 (0..31), col pair cp = (tid&7)*2 ----
  const int erow = tid >> 3;
  const int cp = (tid & 7) * 2;
  float creg[2];
  {
    const float* cs = cb + (size_t)(rb + erow) * HH + hc0 + cp;
    creg[0] = cs[0];
    creg[1] = cs[1];
  }

  __syncthreads();

  for (int t = t0; t < t0 + ct; ++t) {
    // ---- prefetch Gx (fp16 pairs) + resets; no dependency on the barrier ----
    const unsigned short* gxb =
        Gx + ((size_t)(t - t0) * BB + (rb + erow)) * FH + hc0 + cp;
    unsigned gxu[4];
#pragma unroll
    for (int g = 0; g < 4; ++g) gxu[g] = *(const unsigned*)(gxb + g * 512);
    const int* rstT = resets + (size_t)t * BB;
    const int rstE = rstT[rb + erow];

    // ---- group barrier: wait until all 32 producers published step t-1 ----
    if (t > t0) {
      if (wid == 0) {
        const int* cw = &cnt[grp * TT + (t - 1)];
        while (__hip_atomic_load(cw, __ATOMIC_RELAXED,
                                 __HIP_MEMORY_SCOPE_AGENT) < 32)
          __builtin_amdgcn_s_sleep(1);
      }
      __syncthreads();
    }

    // ---- stage h: batched relaxed L3 loads -> swizzled LDS ----
    {
      unsigned* hsrc = ((t & 1) ? hbB : hbA) + (size_t)rb * 256;
      unsigned hv[32];
#pragma unroll
      for (int it = 0; it < 32; ++it)
        hv[it] = __hip_atomic_load(&hsrc[it * 256 + tid], __ATOMIC_RELAXED,
                                   __HIP_MEMORY_SCOPE_AGENT);
#pragma unroll
      for (int it = 0; it < 32; ++it) {
        unsigned v = (rstT[rb + it] != 0) ? 0u : hv[it];
        *(unsigned*)((char*)ah + ((it * 1024 + tid * 4) ^ ((it & 7) << 4))) = v;
      }
    }
    __syncthreads();

    // ---- MFMA: ALL 4 waves; wave wid computes gate wid (16 cols) x 32 rows ----
    {
      const int sw = (lc & 7) << 4;
      f32x4 acc[2] = {};
#pragma unroll
      for (int kk = 0; kk < 16; ++kk) {
        const int kb = kk * 64 + kg * 16;
        short8 a0 = *(const short8*)((char*)ah + ((lc * 1024 + kb) ^ sw));
        short8 a1 = *(const short8*)((char*)ah + (((lc + 16) * 1024 + kb) ^ sw));
        short8 b = *(const short8*)((char*)whs +
                      (((wid * 16 + lc) * 1024 + kb) ^ sw));
        acc[0] = __builtin_amdgcn_mfma_f32_16x16x32_bf16(a0, b, acc[0], 0, 0, 0);
        acc[1] = __builtin_amdgcn_mfma_f32_16x16x32_bf16(a1, b, acc[1], 0, 0, 0);
      }
#pragma unroll
      for (int m = 0; m < 2; ++m)
#pragma unroll
        for (int jj = 0; jj < 4; ++jj)
          gex[wid * 544 + (m * 16 + kg * 4 + jj) * 17 + lc] = acc[m][jj];
    }
    __syncthreads();

    // ---- epilogue: thread owns (erow, cols cp, cp+1) ----
    {
      unsigned* hdst = (t & 1) ? hbA : hbB;
      const int gb = erow * 17 + cp;
      float gi0 = gex[0 * 544 + gb] + h2f((unsigned short)(gxu[0] & 0xffffu));
      float gi1 = gex[0 * 544 + gb + 1] + h2f((unsigned short)(gxu[0] >> 16));
      float gf0 = gex[1 * 544 + gb] + h2f((unsigned short)(gxu[1] & 0xffffu));
      float gf1 = gex[1 * 544 + gb + 1] + h2f((unsigned short)(gxu[1] >> 16));
      float gg0 = gex[2 * 544 + gb] + h2f((unsigned short)(gxu[2] & 0xffffu));
      float gg1 = gex[2 * 544 + gb + 1] + h2f((unsigned short)(gxu[2] >> 16));
      float go0 = gex[3 * 544 + gb] + h2f((unsigned short)(gxu[3] & 0xffffu));
      float go1 = gex[3 * 544 + gb + 1] + h2f((unsigned short)(gxu[3] >> 16));
      float cold0 = rstE ? 0.f : creg[0];
      float cold1 = rstE ? 0.f : creg[1];
      float cn0 = sigm(gf0) * cold0 + sigm(gi0) * tanh_fast(gg0);
      float cn1 = sigm(gf1) * cold1 + sigm(gi1) * tanh_fast(gg1);
      float hn0 = sigm(go0) * tanh_fast(cn0);
      float hn1 = sigm(go1) * tanh_fast(cn1);
      creg[0] = cn0;
      creg[1] = cn1;
      unsigned pack = (unsigned)(unsigned short)f2bf(hn0) |
                      ((unsigned)(unsigned short)f2bf(hn1) << 16);
      __hip_atomic_store(&hdst[(size_t)(rb + erow) * 256 + (hc0 >> 1) + (tid & 7)],
                         pack, __ATOMIC_RELAXED, __HIP_MEMORY_SCOPE_AGENT);
      asm volatile("s_waitcnt vmcnt(0)" ::: "memory");  // h store acked (this thread)
      __syncthreads();                                  // all threads' h stores done
      if (tid == 0)
        __hip_atomic_fetch_add(&cnt[grp * TT + t], 1, __ATOMIC_RELAXED,
                               __HIP_MEMORY_SCOPE_AGENT);
      // ys / finals AFTER the signal: off the critical path
      size_t gidx = (size_t)(rb + erow) * HH + hc0 + cp;
      *(f32x2*)(out + (size_t)t * BB * HH + gidx) = (f32x2){hn0, hn1};
      if (t == TT - 1) {
        out[(size_t)TT * BB * HH + gidx] = cn0;
        out[(size_t)TT * BB * HH + gidx + 1] = cn1;
        out[(size_t)TT * BB * HH + (size_t)BB * HH + gidx] = hn0;
        out[(size_t)TT * BB * HH + (size_t)BB * HH + gidx + 1] = hn1;
      }
    }
  }

  // carry c to next chunk
  {
    float* cs = cb + (size_t)(rb + erow) * HH + hc0 + cp;
    cs[0] = creg[0];
    cs[1] = creg[1];
  }
}

// ---- fallback path (tiny ws): full-K per-step kernel ----
__global__ __launch_bounds__(64) void lstm_step_fullk(
    const float* __restrict__ xt, const int* __restrict__ rst,
    const float* __restrict__ bias, const short* __restrict__ WiT,
    const short* __restrict__ WhT, const short* __restrict__ hin,
    short* __restrict__ hout, float* __restrict__ cbuf, float* __restrict__ ys) {
  const int lane = threadIdx.x;
  const int lc = lane & 15;
  const int kg = lane >> 4;
  const int r0 = blockIdx.x * 16;
  const int h0 = blockIdx.y * 16;
  const int hc = h0 + lc;

  float coldv[4];
  int rstj[4];
#pragma unroll
  for (int jj = 0; jj < 4; ++jj) {
    int row = r0 + kg * 4 + jj;
    rstj[jj] = rst[row];
    coldv[jj] = cbuf[(size_t)row * HH + hc];
  }

  const int rowA = r0 + lc;
  const bool rm = rst[rowA] != 0;
  const short8 zero = {};
  f32x4 acc[4] = {};
#pragma unroll
  for (int kk = 0; kk < 16; ++kk) {
    const int ko = kk * 32 + kg * 8;
    f32x4 u0 = *(const f32x4*)(xt + (size_t)rowA * HH + ko);
    f32x4 u1 = *(const f32x4*)(xt + (size_t)rowA * HH + ko + 4);
    short8 a;
#pragma unroll
    for (int e = 0; e < 4; ++e) { a[e] = f2bf(u0[e]); a[e + 4] = f2bf(u1[e]); }
#pragma unroll
    for (int g = 0; g < 4; ++g) {
      const short8 b = *(const short8*)(WiT + (size_t)(g * HH + h0 + lc) * HH + ko);
      acc[g] = __builtin_amdgcn_mfma_f32_16x16x32_bf16(a, b, acc[g], 0, 0, 0);
    }
  }
#pragma unroll
  for (int kk = 0; kk < 16; ++kk) {
    const int ko = kk * 32 + kg * 8;
    short8 a = rm ? zero : *(const short8*)(hin + (size_t)rowA * HH + ko);
#pragma unroll
    for (int g = 0; g < 4; ++g) {
      const short8 b = *(const short8*)(WhT + (size_t)(g * HH + h0 + lc) * HH + ko);
      acc[g] = __builtin_amdgcn_mfma_f32_16x16x32_bf16(a, b, acc[g], 0, 0, 0);
    }
  }

#pragma unroll
  for (int jj = 0; jj < 4; ++jj) {
    int row = r0 + kg * 4 + jj;
    float gi = acc[0][jj] + bias[0 * HH + hc];
    float gf = acc[1][jj] + bias[1 * HH + hc];
    float gg = acc[2][jj] + bias[2 * HH + hc];
    float go = acc[3][jj] + bias[3 * HH + hc];
    float cold = rstj[jj] ? 0.f : coldv[jj];
    float cn = sigm(gf) * cold + sigm(gi) * tanh_fast(gg);
    float hn = sigm(go) * tanh_fast(cn);
    cbuf[(size_t)row * HH + hc] = cn;
    hout[(size_t)row * HH + hc] = f2bf(hn);
    ys[(size_t)row * HH + hc] = hn;
  }
}

__global__ void finalize_kernel(const float* __restrict__ cbuf, float* __restrict__ out) {
  int i = blockIdx.x * blockDim.x + threadIdx.x;
  if (i < BB * HH) {
    size_t base = (size_t)TT * BB * HH;
    out[base + i] = cbuf[i];
    out[base + BB * HH + i] = out[(size_t)(TT - 1) * BB * HH + i];
  }
}

extern "C" void kernel_launch(void* const* d_in, const int* in_sizes, int n_in,
                              void* d_out, int out_size, void* d_ws, size_t ws_size,
                              hipStream_t stream) {
  const float* x      = (const float*)d_in[0];
  const int*   resets = (const int*)d_in[1];
  const float* c0     = (const float*)d_in[2];
  const float* h0     = (const float*)d_in[3];
  const float* Wi     = (const float*)d_in[4];
  const float* Wh     = (const float*)d_in[5];
  const float* bias   = (const float*)d_in[6];
  float* out = (float*)d_out;

  char* ws = (char*)d_ws;
  short* WiT = (short*)ws;                                         // 2 MiB
  short* WhT = (short*)(ws + (2u << 20));                          // 2 MiB
  unsigned* hb0 = (unsigned*)(ws + (4u << 20));                    // 256 KiB
  unsigned* hb1 = (unsigned*)(ws + (4u << 20) + (256u << 10));     // 256 KiB
  float* cb  = (float*)(ws + (4u << 20) + (512u << 10));           // 512 KiB
  short* hbf0 = (short*)(ws + (5u << 20));                         // 256 KiB (fallback)
  short* hbf1 = hbf0 + BB * HH;                                    // 256 KiB (fallback)
  int*   cnt = (int*)(ws + (5u << 20) + (512u << 10));             // 16 KiB counters
  const size_t GX_OFF = (6u << 20);
  unsigned short* Gx = (unsigned short*)(ws + GX_OFF);

  const size_t perT = (size_t)BB * FH * 2;                         // 1 MiB/step fp16
  int chunkT = 0;
  if (ws_size > GX_OFF + perT) chunkT = (int)((ws_size - GX_OFF) / perT);
  if (chunkT > TT) chunkT = TT;
  chunkT &= ~3;   // multiple of 4: h-parity alignment + swizzle divisibility

  prep_w<<<512, 256, 0, stream>>>(Wi, Wh, WiT, WhT);
  prep_kernel<<<512, 256, 0, stream>>>(h0, c0, hb0, cb, hbf0, cnt);

  if (chunkT >= 4) {
    for (int t0 = 0; t0 < TT; t0 += chunkT) {
      int ct = (TT - t0 < chunkT) ? (TT - t0) : chunkT;
      precomp_kernel<<<ct * 32, 256, 0, stream>>>(x, WiT, bias, Gx,
                                                  t0 * BB);
      lstm_persist<<<256, 256, 65536, stream>>>(resets, WhT, Gx, hb0, hb1,
                                                cb, out, cnt, t0, ct);
    }
  } else {
    for (int t = 0; t < TT; ++t) {
      const short* hin = (t & 1) ? hbf1 : hbf0;
      short* hout      = (t & 1) ? hbf0 : hbf1;
      lstm_step_fullk<<<dim3(16, 32), 64, 0, stream>>>(
          x + (size_t)t * BB * HH, resets + (size_t)t * BB, bias, WiT, WhT,
          hin, hout, cb, out + (size_t)t * BB * HH);
    }
    finalize_kernel<<<(BB * HH + 255) / 256, 256, 0, stream>>>(cb, out);
  }
}

// Round 15
// 2345.108 us; speedup vs baseline: 1.0775x; 1.0775x over previous
//
#include <hip/hip_runtime.h>

#define TT 512
#define BB 256
#define HH 512
#define FH 2048   // 4*H

typedef __attribute__((ext_vector_type(8))) short short8;
typedef __attribute__((ext_vector_type(4))) short short4v;
typedef __attribute__((ext_vector_type(4))) float f32x4;
typedef __attribute__((ext_vector_type(2))) float f32x2;

__device__ __forceinline__ short f2bf(float f) {
  union { float f; unsigned u; } v; v.f = f;
  unsigned r = v.u + 0x7fffu + ((v.u >> 16) & 1u);   // RNE
  return (short)(r >> 16);
}
__device__ __forceinline__ unsigned short f2h(float f) {
  union { _Float16 h; unsigned short u; } v;
  v.h = (_Float16)f;
  return v.u;
}
__device__ __forceinline__ float h2f(unsigned short u) {
  union { _Float16 h; unsigned short u; } v;
  v.u = u;
  return (float)v.h;
}

__device__ __forceinline__ float sigm(float x) {
  return 1.f / (1.f + __expf(-x));
}
__device__ __forceinline__ float tanh_fast(float x) {
  float e = __expf(2.f * x);
  return 1.f - 2.f / (e + 1.f);
}

// async global->LDS, 16B per lane; lds dest must be wave-uniform base (HW adds lane*16).
__device__ __forceinline__ void gload16(const void* g, void* l) {
  __builtin_amdgcn_global_load_lds(
      (const __attribute__((address_space(1))) unsigned*)g,
      (__attribute__((address_space(3))) unsigned*)(unsigned)(unsigned long long)l,
      16, 0, 0);
}

// LDS-tiled coalesced weight transpose: Wi/Wh (512 k x 2048 col, fp32, row-major)
// -> WiT/WhT (2048 col x 512 k, bf16). 64x64 tiles; both global sides coalesced.
__global__ __launch_bounds__(256) void prep_w(
    const float* __restrict__ Wi, const float* __restrict__ Wh,
    short* __restrict__ WiT, short* __restrict__ WhT) {
  __shared__ short t[64][65];     // [k][c], +1 pad
  const int w = blockIdx.x >> 8;            // 0: Wi, 1: Wh
  const int tile = blockIdx.x & 255;
  const int c0 = (tile & 31) * 64;
  const int k0 = (tile >> 5) * 64;
  const float* src = w ? Wh : Wi;
  short* dst = w ? WhT : WiT;
  const int tid = threadIdx.x;

  {
    const int r = tid >> 2;                 // 0..63
    const int cq = (tid & 3) * 16;
#pragma unroll
    for (int i = 0; i < 4; ++i) {
      f32x4 v = *(const f32x4*)(src + (size_t)(k0 + r) * FH + c0 + cq + i * 4);
      short4v s = { f2bf(v[0]), f2bf(v[1]), f2bf(v[2]), f2bf(v[3]) };
      *(short4v*)(&t[r][cq + i * 4]) = s;
    }
  }
  __syncthreads();

  {
    const int c = tid >> 2;                 // 0..63
    const int kq = (tid & 3) * 16;
    short8 o0, o1;
#pragma unroll
    for (int e = 0; e < 8; ++e) {
      o0[e] = t[kq + e][c];
      o1[e] = t[kq + 8 + e][c];
    }
    short* d = dst + (size_t)(c0 + c) * 512 + k0 + kq;
    *(short8*)d = o0;
    *(short8*)(d + 8) = o1;
  }
}

// prep misc: X -> bf16, packed h init, c init, counters, fallback h.
__global__ void prep_kernel(const float* __restrict__ h0, const float* __restrict__ c0,
                            const float* __restrict__ x,
                            unsigned* __restrict__ hb0, float* __restrict__ cb,
                            short* __restrict__ hbf, short* __restrict__ Xb,
                            int* __restrict__ cnt) {
  int idx = blockIdx.x * blockDim.x + threadIdx.x;
  int stride = gridDim.x * blockDim.x;
  for (int i = idx; i < BB * HH; i += stride) {
    hbf[i] = f2bf(h0[i]);
    cb[i] = c0[i];
  }
  for (int i = idx; i < BB * 256; i += stride) {
    int row = i >> 8;
    int cpx = (i & 255) * 2;
    hb0[i] = (unsigned)(unsigned short)f2bf(h0[(size_t)row * HH + cpx]) |
             ((unsigned)(unsigned short)f2bf(h0[(size_t)row * HH + cpx + 1]) << 16);
  }
  for (int i = idx; i < 8 * TT; i += stride) cnt[i] = 0;
  // X fp32 -> bf16 (one-time pass; halves precomp's A-side stream)
  const size_t nx4 = (size_t)TT * BB * HH / 4;
  for (size_t i = idx; i < nx4; i += stride) {
    f32x4 v = *(const f32x4*)(x + i * 4);
    short4v s = { f2bf(v[0]), f2bf(v[1]), f2bf(v[2]), f2bf(v[3]) };
    *(short4v*)(Xb + i * 4) = s;
  }
}

// 128x128-tile GEMM: Gx16 = fp16(Xb @ WiT^T + bias). m97 structure
// (global_load_lds width-16, linear LDS) + XCD-aware flat-grid swizzle.
__global__ __launch_bounds__(256) void precomp_kernel(
    const short* __restrict__ Xb, const short* __restrict__ WiT,
    const float* __restrict__ bias, unsigned short* __restrict__ Gx,
    int rowBase) {
  __shared__ short As[128 * 64];
  __shared__ short Bs[128 * 64];

  const int tid = threadIdx.x;

  int coltile, rowtile;
  if ((gridDim.x & 127) == 0) {
    const int b = blockIdx.x;
    const int xcd = b & 7;
    const int i = b >> 3;
    rowtile = (i >> 4) * 8 + xcd;
    coltile = i & 15;
  } else {
    coltile = blockIdx.x & 15;
    rowtile = blockIdx.x >> 4;
  }
  const int cb0 = coltile * 128;
  const int rb = rowtile * 128;
  const size_t grow = (size_t)rowBase + rb;

  const int wid = tid >> 6;
  const int lane = tid & 63;
  const int lc = lane & 15;
  const int kg = lane >> 4;
  const int m0 = (wid >> 1) * 64;
  const int n0 = (wid & 1) * 64;

  // staging geometry: wave w instr i stages 8 rows (1KB): rows w*32 + i*8 .. +8
  const int srow0 = wid * 32;
  const int lrow = lane >> 3;
  const int lkc = lane & 7;

  f32x4 acc[4][4] = {};

  for (int kt = 0; kt < 8; ++kt) {
    const int k0 = kt * 64;
    __syncthreads();
#pragma unroll
    for (int i = 0; i < 4; ++i) {
      const int row = srow0 + i * 8 + lrow;
      gload16(Xb + (grow + row) * 512 + k0 + lkc * 8,
              (char*)As + (size_t)(srow0 + i * 8) * 128);
      gload16(WiT + (size_t)(cb0 + row) * 512 + k0 + lkc * 8,
              (char*)Bs + (size_t)(srow0 + i * 8) * 128);
    }
    __syncthreads();

#pragma unroll
    for (int ks = 0; ks < 2; ++ks) {
      const int kb = ks * 64 + kg * 16;
      short8 af[4], bf[4];
#pragma unroll
      for (int m = 0; m < 4; ++m)
        af[m] = *(const short8*)((char*)As + (m0 + m * 16 + lc) * 128 + kb);
#pragma unroll
      for (int n = 0; n < 4; ++n)
        bf[n] = *(const short8*)((char*)Bs + (n0 + n * 16 + lc) * 128 + kb);
#pragma unroll
      for (int m = 0; m < 4; ++m)
#pragma unroll
        for (int n = 0; n < 4; ++n)
          acc[m][n] = __builtin_amdgcn_mfma_f32_16x16x32_bf16(af[m], bf[n],
                                                              acc[m][n], 0, 0, 0);
    }
  }

#pragma unroll
  for (int n = 0; n < 4; ++n) {
    const int col = cb0 + n0 + n * 16 + lc;
    const float bv = bias[col];
#pragma unroll
    for (int m = 0; m < 4; ++m) {
      const int rloc = rb + m0 + m * 16 + kg * 4;
#pragma unroll
      for (int j = 0; j < 4; ++j)
        Gx[(size_t)(rloc + j) * FH + col] = f2h(acc[m][n][j] + bv);
    }
  }
}

// Persistent step kernel (R11 structure; sync = single counter per (grp,t)):
// 256 blocks = 8 groups x 32 col-groups, 256 threads; MFMA split across 4
// waves (wave = 1 gate x 32 rows); h via relaxed agent atomics; producer
// fetch_add after publish->vmcnt(0)->barrier; wave-0 polls one word, s_sleep(1).
__global__ __launch_bounds__(256) void lstm_persist(
    const int* __restrict__ resets,         // (T,B)
    const short* __restrict__ WhT,          // (2048,512) bf16 bits
    const unsigned short* __restrict__ Gx,  // (ct,B,2048) fp16, bias included
    unsigned* __restrict__ hbA,             // (B,256) u32 bf16-pairs, parity 0
    unsigned* __restrict__ hbB,             // parity 1
    float* __restrict__ cb,                 // (B,H) c state (chunk carry)
    float* __restrict__ out,                // output base
    int* __restrict__ cnt,                  // (8,T) counters
    int t0, int ct) {
  extern __shared__ short whs[];          // 64 gate-cols x 512 k, swizzled (64 KB)
  __shared__ short ah[32 * 512];          // 32 rows x 512 k, swizzled (32 KB)
  __shared__ float gex[4 * 32 * 17];      // gate exchange (8.5 KB)

  const int tid = threadIdx.x;
  const int bid = blockIdx.x;
  const int grp = bid >> 5;          // batch group 0..7
  const int j = bid & 31;            // col group
  const int rb = grp * 32;
  const int hc0 = j * 16;

  const int wid = tid >> 6;
  const int lane = tid & 63;
  const int lc = lane & 15;
  const int kg = lane >> 4;

  // ---- Wh slice -> LDS (once, swizzled) ----
  {
    const int lcol = tid >> 2;            // 0..63 gate-col
    const int part = tid & 3;             // 128-short quarters
    const int g = lcol >> 4;
    const int gcol = g * 512 + hc0 + (lcol & 15);
    const short* src = WhT + (size_t)gcol * 512 + part * 128;
    const int dbase = lcol * 1024 + part * 256;
    const int sw = (lcol & 7) << 4;
#pragma unroll
    for (int it = 0; it < 16; ++it) {
      short8 v = *(const short8*)(src + it * 8);
      *(short8*)((char*)whs + ((dbase + it * 16) ^ sw)) = v;
    }
  }

  // ---- epilogue ownership: row = tid>>3 (0..31), col pair cp = (tid&7)*2 ----
  const int erow = tid >> 3;
  const int cp = (tid & 7) * 2;
  float creg[2];
  {
    const float* cs = cb + (size_t)(rb + erow) * HH + hc0 + cp;
    creg[0] = cs[0];
    creg[1] = cs[1];
  }

  __syncthreads();

  for (int t = t0; t < t0 + ct; ++t) {
    // ---- prefetch Gx (fp16 pairs) + resets; no dependency on the barrier ----
    const unsigned short* gxb =
        Gx + ((size_t)(t - t0) * BB + (rb + erow)) * FH + hc0 + cp;
    unsigned gxu[4];
#pragma unroll
    for (int g = 0; g < 4; ++g) gxu[g] = *(const unsigned*)(gxb + g * 512);
    const int* rstT = resets + (size_t)t * BB;
    const int rstE = rstT[rb + erow];

    // ---- group barrier: wait until all 32 producers published step t-1 ----
    if (t > t0) {
      if (wid == 0) {
        const int* cw = &cnt[grp * TT + (t - 1)];
        while (__hip_atomic_load(cw, __ATOMIC_RELAXED,
                                 __HIP_MEMORY_SCOPE_AGENT) < 32)
          __builtin_amdgcn_s_sleep(1);
      }
      __syncthreads();
    }

    // ---- stage h: batched relaxed L3 loads -> swizzled LDS ----
    {
      unsigned* hsrc = ((t & 1) ? hbB : hbA) + (size_t)rb * 256;
      unsigned hv[32];
#pragma unroll
      for (int it = 0; it < 32; ++it)
        hv[it] = __hip_atomic_load(&hsrc[it * 256 + tid], __ATOMIC_RELAXED,
                                   __HIP_MEMORY_SCOPE_AGENT);
#pragma unroll
      for (int it = 0; it < 32; ++it) {
        unsigned v = (rstT[rb + it] != 0) ? 0u : hv[it];
        *(unsigned*)((char*)ah + ((it * 1024 + tid * 4) ^ ((it & 7) << 4))) = v;
      }
    }
    __syncthreads();

    // ---- MFMA: ALL 4 waves; wave wid computes gate wid (16 cols) x 32 rows ----
    {
      const int sw = (lc & 7) << 4;
      f32x4 acc[2] = {};
#pragma unroll
      for (int kk = 0; kk < 16; ++kk) {
        const int kb = kk * 64 + kg * 16;
        short8 a0 = *(const short8*)((char*)ah + ((lc * 1024 + kb) ^ sw));
        short8 a1 = *(const short8*)((char*)ah + (((lc + 16) * 1024 + kb) ^ sw));
        short8 b = *(const short8*)((char*)whs +
                      (((wid * 16 + lc) * 1024 + kb) ^ sw));
        acc[0] = __builtin_amdgcn_mfma_f32_16x16x32_bf16(a0, b, acc[0], 0, 0, 0);
        acc[1] = __builtin_amdgcn_mfma_f32_16x16x32_bf16(a1, b, acc[1], 0, 0, 0);
      }
#pragma unroll
      for (int m = 0; m < 2; ++m)
#pragma unroll
        for (int jj = 0; jj < 4; ++jj)
          gex[wid * 544 + (m * 16 + kg * 4 + jj) * 17 + lc] = acc[m][jj];
    }
    __syncthreads();

    // ---- epilogue: thread owns (erow, cols cp, cp+1) ----
    {
      unsigned* hdst = (t & 1) ? hbA : hbB;
      const int gb = erow * 17 + cp;
      float gi0 = gex[0 * 544 + gb] + h2f((unsigned short)(gxu[0] & 0xffffu));
      float gi1 = gex[0 * 544 + gb + 1] + h2f((unsigned short)(gxu[0] >> 16));
      float gf0 = gex[1 * 544 + gb] + h2f((unsigned short)(gxu[1] & 0xffffu));
      float gf1 = gex[1 * 544 + gb + 1] + h2f((unsigned short)(gxu[1] >> 16));
      float gg0 = gex[2 * 544 + gb] + h2f((unsigned short)(gxu[2] & 0xffffu));
      float gg1 = gex[2 * 544 + gb + 1] + h2f((unsigned short)(gxu[2] >> 16));
      float go0 = gex[3 * 544 + gb] + h2f((unsigned short)(gxu[3] & 0xffffu));
      float go1 = gex[3 * 544 + gb + 1] + h2f((unsigned short)(gxu[3] >> 16));
      float cold0 = rstE ? 0.f : creg[0];
      float cold1 = rstE ? 0.f : creg[1];
      float cn0 = sigm(gf0) * cold0 + sigm(gi0) * tanh_fast(gg0);
      float cn1 = sigm(gf1) * cold1 + sigm(gi1) * tanh_fast(gg1);
      float hn0 = sigm(go0) * tanh_fast(cn0);
      float hn1 = sigm(go1) * tanh_fast(cn1);
      creg[0] = cn0;
      creg[1] = cn1;
      unsigned pack = (unsigned)(unsigned short)f2bf(hn0) |
                      ((unsigned)(unsigned short)f2bf(hn1) << 16);
      __hip_atomic_store(&hdst[(size_t)(rb + erow) * 256 + (hc0 >> 1) + (tid & 7)],
                         pack, __ATOMIC_RELAXED, __HIP_MEMORY_SCOPE_AGENT);
      asm volatile("s_waitcnt vmcnt(0)" ::: "memory");  // h store acked (this thread)
      __syncthreads();                                  // all threads' h stores done
      if (tid == 0)
        __hip_atomic_fetch_add(&cnt[grp * TT + t], 1, __ATOMIC_RELAXED,
                               __HIP_MEMORY_SCOPE_AGENT);
      // ys / finals AFTER the signal: off the critical path
      size_t gidx = (size_t)(rb + erow) * HH + hc0 + cp;
      *(f32x2*)(out + (size_t)t * BB * HH + gidx) = (f32x2){hn0, hn1};
      if (t == TT - 1) {
        out[(size_t)TT * BB * HH + gidx] = cn0;
        out[(size_t)TT * BB * HH + gidx + 1] = cn1;
        out[(size_t)TT * BB * HH + (size_t)BB * HH + gidx] = hn0;
        out[(size_t)TT * BB * HH + (size_t)BB * HH + gidx + 1] = hn1;
      }
    }
  }

  // carry c to next chunk
  {
    float* cs = cb + (size_t)(rb + erow) * HH + hc0 + cp;
    cs[0] = creg[0];
    cs[1] = creg[1];
  }
}

// ---- fallback path (tiny ws): full-K per-step kernel ----
__global__ __launch_bounds__(64) void lstm_step_fullk(
    const float* __restrict__ xt, const int* __restrict__ rst,
    const float* __restrict__ bias, const short* __restrict__ WiT,
    const short* __restrict__ WhT, const short* __restrict__ hin,
    short* __restrict__ hout, float* __restrict__ cbuf, float* __restrict__ ys) {
  const int lane = threadIdx.x;
  const int lc = lane & 15;
  const int kg = lane >> 4;
  const int r0 = blockIdx.x * 16;
  const int h0 = blockIdx.y * 16;
  const int hc = h0 + lc;

  float coldv[4];
  int rstj[4];
#pragma unroll
  for (int jj = 0; jj < 4; ++jj) {
    int row = r0 + kg * 4 + jj;
    rstj[jj] = rst[row];
    coldv[jj] = cbuf[(size_t)row * HH + hc];
  }

  const int rowA = r0 + lc;
  const bool rm = rst[rowA] != 0;
  const short8 zero = {};
  f32x4 acc[4] = {};
#pragma unroll
  for (int kk = 0; kk < 16; ++kk) {
    const int ko = kk * 32 + kg * 8;
    f32x4 u0 = *(const f32x4*)(xt + (size_t)rowA * HH + ko);
    f32x4 u1 = *(const f32x4*)(xt + (size_t)rowA * HH + ko + 4);
    short8 a;
#pragma unroll
    for (int e = 0; e < 4; ++e) { a[e] = f2bf(u0[e]); a[e + 4] = f2bf(u1[e]); }
#pragma unroll
    for (int g = 0; g < 4; ++g) {
      const short8 b = *(const short8*)(WiT + (size_t)(g * HH + h0 + lc) * HH + ko);
      acc[g] = __builtin_amdgcn_mfma_f32_16x16x32_bf16(a, b, acc[g], 0, 0, 0);
    }
  }
#pragma unroll
  for (int kk = 0; kk < 16; ++kk) {
    const int ko = kk * 32 + kg * 8;
    short8 a = rm ? zero : *(const short8*)(hin + (size_t)rowA * HH + ko);
#pragma unroll
    for (int g = 0; g < 4; ++g) {
      const short8 b = *(const short8*)(WhT + (size_t)(g * HH + h0 + lc) * HH + ko);
      acc[g] = __builtin_amdgcn_mfma_f32_16x16x32_bf16(a, b, acc[g], 0, 0, 0);
    }
  }

#pragma unroll
  for (int jj = 0; jj < 4; ++jj) {
    int row = r0 + kg * 4 + jj;
    float gi = acc[0][jj] + bias[0 * HH + hc];
    float gf = acc[1][jj] + bias[1 * HH + hc];
    float gg = acc[2][jj] + bias[2 * HH + hc];
    float go = acc[3][jj] + bias[3 * HH + hc];
    float cold = rstj[jj] ? 0.f : coldv[jj];
    float cn = sigm(gf) * cold + sigm(gi) * tanh_fast(gg);
    float hn = sigm(go) * tanh_fast(cn);
    cbuf[(size_t)row * HH + hc] = cn;
    hout[(size_t)row * HH + hc] = f2bf(hn);
    ys[(size_t)row * HH + hc] = hn;
  }
}

__global__ void finalize_kernel(const float* __restrict__ cbuf, float* __restrict__ out) {
  int i = blockIdx.x * blockDim.x + threadIdx.x;
  if (i < BB * HH) {
    size_t base = (size_t)TT * BB * HH;
    out[base + i] = cbuf[i];
    out[base + BB * HH + i] = out[(size_t)(TT - 1) * BB * HH + i];
  }
}

extern "C" void kernel_launch(void* const* d_in, const int* in_sizes, int n_in,
                              void* d_out, int out_size, void* d_ws, size_t ws_size,
                              hipStream_t stream) {
  const float* x      = (const float*)d_in[0];
  const int*   resets = (const int*)d_in[1];
  const float* c0     = (const float*)d_in[2];
  const float* h0     = (const float*)d_in[3];
  const float* Wi     = (const float*)d_in[4];
  const float* Wh     = (const float*)d_in[5];
  const float* bias   = (const float*)d_in[6];
  float* out = (float*)d_out;

  char* ws = (char*)d_ws;
  short* WiT = (short*)ws;                                         // 2 MiB
  short* WhT = (short*)(ws + (2u << 20));                          // 2 MiB
  unsigned* hb0 = (unsigned*)(ws + (4u << 20));                    // 256 KiB
  unsigned* hb1 = (unsigned*)(ws + (4u << 20) + (256u << 10));     // 256 KiB
  float* cb  = (float*)(ws + (4u << 20) + (512u << 10));           // 512 KiB
  short* hbf0 = (short*)(ws + (5u << 20));                         // 256 KiB (fallback)
  short* hbf1 = hbf0 + BB * HH;                                    // 256 KiB (fallback)
  int*   cnt = (int*)(ws + (5u << 20) + (512u << 10));             // 16 KiB counters
  short* Xb  = (short*)(ws + (6u << 20));                          // 128 MiB
  const size_t GX_OFF = (6u << 20) + (size_t)TT * BB * HH * 2;     // 134 MiB
  unsigned short* Gx = (unsigned short*)(ws + GX_OFF);

  const size_t perT = (size_t)BB * FH * 2;                         // 1 MiB/step fp16
  int chunkT = 0;
  if (ws_size > GX_OFF + perT) chunkT = (int)((ws_size - GX_OFF) / perT);
  if (chunkT > TT) chunkT = TT;
  chunkT &= ~3;   // multiple of 4: h-parity alignment + swizzle divisibility

  prep_w<<<512, 256, 0, stream>>>(Wi, Wh, WiT, WhT);
  prep_kernel<<<2048, 256, 0, stream>>>(h0, c0, x, hb0, cb, hbf0, Xb, cnt);

  if (chunkT >= 4) {
    for (int t0 = 0; t0 < TT; t0 += chunkT) {
      int ct = (TT - t0 < chunkT) ? (TT - t0) : chunkT;
      precomp_kernel<<<ct * 32, 256, 0, stream>>>(Xb, WiT, bias, Gx, t0 * BB);
      lstm_persist<<<256, 256, 65536, stream>>>(resets, WhT, Gx, hb0, hb1,
                                                cb, out, cnt, t0, ct);
    }
  } else {
    for (int t = 0; t < TT; ++t) {
      const short* hin = (t & 1) ? hbf1 : hbf0;
      short* hout      = (t & 1) ? hbf0 : hbf1;
      lstm_step_fullk<<<dim3(16, 32), 64, 0, stream>>>(
          x + (size_t)t * BB * HH, resets + (size_t)t * BB, bias, WiT, WhT,
          hin, hout, cb, out + (size_t)t * BB * HH);
    }
    finalize_kernel<<<(BB * HH + 255) / 256, 256, 0, stream>>>(cb, out);
  }
}